// Round 4
// baseline (113.567 us; speedup 1.0000x reference)
//
#include <hip/hip_runtime.h>
#include <hip/hip_bf16.h>

#define F_   512
#define FF_  (512 * 512)
#define C_   128

typedef __attribute__((ext_vector_type(4))) float f32x4;
typedef __attribute__((ext_vector_type(8))) short s16x8;
typedef __attribute__((ext_vector_type(4))) unsigned short u16x4;

__device__ __forceinline__ unsigned short f2bf(float f) {
    union { __hip_bfloat16 h; unsigned short u; } c;
    c.h = __float2bfloat16(f);          // RNE; compiler fuses pairs to v_cvt_pk_bf16_f32
    return c.u;
}

__device__ __forceinline__ s16x8 pack8(f32x4 lo, f32x4 hi) {
    s16x8 r;
    r[0] = (short)f2bf(lo[0]); r[1] = (short)f2bf(lo[1]);
    r[2] = (short)f2bf(lo[2]); r[3] = (short)f2bf(lo[3]);
    r[4] = (short)f2bf(hi[0]); r[5] = (short)f2bf(hi[1]);
    r[6] = (short)f2bf(hi[2]); r[7] = (short)f2bf(hi[3]);
    return r;
}

#define GLDS16(gp, lp)                                                         \
    __builtin_amdgcn_global_load_lds(                                          \
        (const __attribute__((address_space(1))) void*)(gp),                   \
        (__attribute__((address_space(3))) void*)(lp), 16, 0, 0)

// ---------------------------------------------------------------------------
// Kernel 1 v5: params = phi @ Wc^T (+bc), mask, -> wT[b][k][i] bf16 + bias.
// 4096 blocks, tile 8i x 8k. Each of 4 waves owns a DISJOINT 8i x 2k cell
// set = its own 16 Wc rows (8 KB), staged wave-privately via contiguous
// global_load_lds (1 KB/inst, source pre-swizzled ^(g<<4)), vmcnt(0) with
// NO barrier, ds_read_b128 (swizzled) -> pack -> 16 MFMA. Fully-masked row
// pairs skip the glds (wave-uniform). One __syncthreads before the
// coalesced transposed store. Blocks 4096+: bias rows.
// ---------------------------------------------------------------------------
__global__ __launch_bounds__(256, 3) void k1_params(
    const float* __restrict__ phi, const float* __restrict__ Wc,
    const float* __restrict__ bc, unsigned short* __restrict__ wT,
    float* __restrict__ biasWS)
{
    const int blk = blockIdx.x;
    const int tid = threadIdx.x;

    if (blk >= 4096) {                      // ---- bias part ----
        int g = ((blk - 4096) << 8) + tid;  // 0..32767
        int k = g >> 6, b = g & 63;         // 64 lanes share one Wc row
        const f32x4* w4 = (const f32x4*)(Wc + (size_t)(FF_ + k) * C_);
        const f32x4* p4 = (const f32x4*)(phi + b * C_);
        float acc = bc[FF_ + k];
#pragma unroll
        for (int c = 0; c < 32; ++c) {
            f32x4 a = w4[c], q = p4[c];
            acc += a[0]*q[0] + a[1]*q[1] + a[2]*q[2] + a[3]*q[3];
        }
        biasWS[(b << 9) + k] = acc;
        return;
    }

    __shared__ __align__(16) char stg[4][8192];              // wave-private stage
    __shared__ __align__(16) unsigned short trans[64 * 72];  // 9.2 KB, 144B b-stride

    const int lane = tid & 63, wave = tid >> 6, quad = lane >> 4;
    const int i0 = (blk >> 6) << 3;     // 64 i-tiles of 8
    const int k0 = (blk & 63) << 3;     // 64 k-tiles of 8
    const int kw = k0 + (wave << 1);    // this wave's 2 k's

    // ---- stage: 8 glds, contiguous 1KB/inst, skip fully-masked row pairs
    {
        int dk0 = kw % 63, dk1 = (kw + 1) % 63;
        int dmin = dk0 < dk1 ? dk0 : dk1;
        const int rsel  = lane >> 5;            // 0/1 -> kw / kw+1
        const int sslot = (lane & 31) << 4;
        char* stw = (char*)stg[wave];
#pragma unroll
        for (int g = 0; g < 8; ++g) {
            if (((i0 + g) % 63) >= dmin) {
                const char* src =
                    (const char*)(Wc + ((size_t)(i0 + g) * F_ + kw + rsel) * C_)
                    + (sslot ^ (g << 4));       // pre-swizzled source
                GLDS16(src, stw + (g << 10));
            }
        }
    }

    // ---- hoist phi A-frags: 4 m-tiles x 4 kk (64 VGPR)
    s16x8 afr[4][4];
    {
        const int brow = lane & 15, cb = quad << 3;
#pragma unroll
        for (int m = 0; m < 4; ++m)
#pragma unroll
            for (int kk = 0; kk < 4; ++kk) {
                const float* p = phi + ((m << 4) + brow) * C_ + kk * 32 + cb;
                afr[m][kk] = pack8(*(const f32x4*)p, *(const f32x4*)(p + 4));
            }
    }

    // ---- per-lane cell: col c -> (il, kl)
    const int c = lane & 15, il = c & 7, kl = c >> 3;
    const int icell = i0 + il, kcell = kw + kl;
    const bool keep = (icell % 63) >= (kcell % 63);
    const float bcv = bc[icell * F_ + kcell];

    asm volatile("s_waitcnt vmcnt(0)" ::: "memory");   // wave-private: no barrier
    __builtin_amdgcn_sched_barrier(0);

    f32x4 acc[4];
#pragma unroll
    for (int m = 0; m < 4; ++m) acc[m] = (f32x4){0.f, 0.f, 0.f, 0.f};

    const char* rowp = (const char*)stg[wave] + (il << 10) + (kl << 9);
#pragma unroll
    for (int kk = 0; kk < 4; ++kk) {
        int y0 = (kk << 7) + (((quad << 5) | 0)  ^ (il << 4));
        int y1 = (kk << 7) + (((quad << 5) | 16) ^ (il << 4));
        f32x4 lo = *(const f32x4*)(rowp + y0);
        f32x4 hi = *(const f32x4*)(rowp + y1);
        s16x8 bfr = pack8(lo, hi);
#pragma unroll
        for (int m = 0; m < 4; ++m)
            acc[m] = __builtin_amdgcn_mfma_f32_16x16x32_bf16(
                afr[m][kk], bfr, acc[m], 0, 0, 0);
    }

    // ---- trans write (rotate slot = (kb+b)&7 to spread store-phase banks)
    const int kb = (wave << 1) + kl;
#pragma unroll
    for (int m = 0; m < 4; ++m)
#pragma unroll
        for (int r = 0; r < 4; ++r) {
            int b = (m << 4) + (quad << 2) + r;
            int slot = (kb + b) & 7;
            trans[b * 72 + slot * 8 + il] =
                keep ? f2bf(acc[m][r] + bcv) : (unsigned short)0;
        }
    __syncthreads();

    // ---- store: 512 chunks x 16B, coalesced
#pragma unroll
    for (int rr = 0; rr < 2; ++rr) {
        int id = (rr << 8) + tid;
        int b = id >> 3, kb2 = id & 7;
        int slot = (kb2 + b) & 7;
        s16x8 v = *(const s16x8*)&trans[b * 72 + slot * 8];
        *(s16x8*)&wT[(((size_t)((b << 9) + k0 + kb2)) << 9) + i0] = v;
    }
}

// ---------------------------------------------------------------------------
// Kernel 2 (structure unchanged; f2bf now compiler cvt): two chained GEMMs
// vs wT + bias, residual epilogue. ~15 us, near BW floor.
// ---------------------------------------------------------------------------
#define SMEM_BOFF 66560           // 64*1040
#define CHUNK_B   32768
#define SMEM_TOT  (66560 + 2 * 32768)   // 132096

__global__ __launch_bounds__(512) void k2_apply(
    const float* __restrict__ X, const unsigned short* __restrict__ wT,
    const float* __restrict__ biasWS, float* __restrict__ out)
{
    extern __shared__ char smem[];
    unsigned short* A_lds = (unsigned short*)smem;

    const int blk = blockIdx.x;
    const int sw  = ((blk & 7) << 5) + (blk >> 3);   // XCD swizzle
    const int b   = sw >> 2;
    const int n0  = (sw & 3) << 6;

    const int tid = threadIdx.x, lane = tid & 63, wave = tid >> 6;
    const int wn = wave >> 2, wk = wave & 3;

    const float* Xb = X + (((size_t)(b * 256 + n0)) << 9);
    float*       Ob = out + (((size_t)(b * 256 + n0)) << 9);
    const unsigned short* wTb = wT + ((size_t)b << 18);

    float biasr[8];
#pragma unroll
    for (int nt = 0; nt < 8; ++nt)
        biasr[nt] = biasWS[(b << 9) + (wk << 7) + (nt << 4) + (lane & 15)];

    // stage relu(X) -> A_lds bf16
    {
        const f32x4* X4 = (const f32x4*)Xb;
#pragma unroll
        for (int j = 0; j < 16; ++j) {
            int f = (j << 9) + tid;
            int row = f >> 7, c4 = f & 127;
            f32x4 v = X4[f];
            u16x4 h;
#pragma unroll
            for (int e = 0; e < 4; ++e) h[e] = f2bf(fmaxf(v[e], 0.f));
            *(u16x4*)&A_lds[row * 520 + (c4 << 2)] = h;
        }
    }

    const int srcslot = ((lane & 3) ^ ((lane >> 3) & 3)) << 3;

    f32x4 acc[2][8];

    for (int phase = 0; phase < 2; ++phase) {
#pragma unroll
        for (int mt = 0; mt < 2; ++mt)
#pragma unroll
            for (int nt = 0; nt < 8; ++nt) acc[mt][nt] = (f32x4){0.f, 0.f, 0.f, 0.f};

#pragma unroll
        for (int g = 0; g < 4; ++g) {
            int krow = (wave << 6) + (g << 4) + (lane >> 2);
            const unsigned short* src = wTb + ((size_t)krow << 9) + srcslot;
            char* lp = smem + SMEM_BOFF + (((wave << 6) + (g << 4)) << 6);
            GLDS16(src, lp);
        }
        asm volatile("s_waitcnt vmcnt(0)" ::: "memory");
        __syncthreads();

        for (int c = 0; c < 16; ++c) {
            const int cur = c & 1;
            if (c < 15) {
                const int i0n = (c + 1) << 5;
#pragma unroll
                for (int g = 0; g < 4; ++g) {
                    int krow = (wave << 6) + (g << 4) + (lane >> 2);
                    const unsigned short* src = wTb + ((size_t)krow << 9) + i0n + srcslot;
                    char* lp = smem + SMEM_BOFF + (cur ^ 1) * CHUNK_B
                             + (((wave << 6) + (g << 4)) << 6);
                    GLDS16(src, lp);
                }
            }
            const int i0c = c << 5;
            s16x8 afr[2];
#pragma unroll
            for (int mt = 0; mt < 2; ++mt) {
                int n = (wn << 5) + (mt << 4) + (lane & 15);
                afr[mt] = *(const s16x8*)&A_lds[n * 520 + i0c + ((lane >> 4) << 3)];
            }
            const unsigned short* Bb =
                (const unsigned short*)(smem + SMEM_BOFF + cur * CHUNK_B);
#pragma unroll
            for (int nt = 0; nt < 8; ++nt) {
                int k = (wk << 7) + (nt << 4) + (lane & 15);
                int slot = (((lane >> 4) ^ ((k >> 1) & 3)) << 3);
                s16x8 bfr = *(const s16x8*)&Bb[(k << 5) + slot];
#pragma unroll
                for (int mt = 0; mt < 2; ++mt)
                    acc[mt][nt] = __builtin_amdgcn_mfma_f32_16x16x32_bf16(
                        afr[mt], bfr, acc[mt][nt], 0, 0, 0);
            }
            asm volatile("s_waitcnt vmcnt(0)" ::: "memory");
            __syncthreads();
        }

        if (phase == 0) {
#pragma unroll
            for (int mt = 0; mt < 2; ++mt)
#pragma unroll
                for (int nt = 0; nt < 8; ++nt) {
                    int k = (wk << 7) + (nt << 4) + (lane & 15);
#pragma unroll
                    for (int r = 0; r < 4; ++r) {
                        int n = (wn << 5) + (mt << 4) + ((lane >> 4) << 2) + r;
                        A_lds[n * 520 + k] =
                            f2bf(fmaxf(acc[mt][nt][r] + biasr[nt], 0.f));
                    }
                }
            __syncthreads();
        }
    }

#pragma unroll
    for (int mt = 0; mt < 2; ++mt)
#pragma unroll
        for (int nt = 0; nt < 8; ++nt) {
            int k = (wk << 7) + (nt << 4) + (lane & 15);
#pragma unroll
            for (int r = 0; r < 4; ++r) {
                int n = (wn << 5) + (mt << 4) + ((lane >> 4) << 2) + r;
                size_t off = ((size_t)n << 9) + k;
                Ob[off] = Xb[off] + acc[mt][nt][r] + biasr[nt];
            }
        }
}

extern "C" void kernel_launch(void* const* d_in, const int* in_sizes, int n_in,
                              void* d_out, int out_size, void* d_ws, size_t ws_size,
                              hipStream_t stream) {
    const float* inputs = (const float*)d_in[0];
    const float* phi    = (const float*)d_in[1];
    const float* Wc     = (const float*)d_in[2];
    const float* bc     = (const float*)d_in[3];
    float* out = (float*)d_out;

    unsigned short* wT = (unsigned short*)d_ws;                         // 32 MiB
    float* biasWS = (float*)((char*)d_ws + (size_t)64 * 512 * 512 * 2); // 64*512 fp32

    hipLaunchKernelGGL(k1_params, dim3(4224), dim3(256), 0, stream,
                       phi, Wc, bc, wT, biasWS);

    hipFuncSetAttribute((const void*)k2_apply,
                        hipFuncAttributeMaxDynamicSharedMemorySize, SMEM_TOT);
    hipLaunchKernelGGL(k2_apply, dim3(256), dim3(512), SMEM_TOT, stream,
                       inputs, wT, biasWS, out);
}

// Round 5
// 86.467 us; speedup vs baseline: 1.3134x; 1.3134x over previous
//
#include <hip/hip_runtime.h>
#include <hip/hip_bf16.h>

#define F_   512
#define FF_  (512 * 512)
#define C_   128

typedef __attribute__((ext_vector_type(4))) float f32x4;
typedef __attribute__((ext_vector_type(8))) short s16x8;
typedef __attribute__((ext_vector_type(4))) unsigned short u16x4;

__device__ __forceinline__ unsigned short f2bf(float f) {
    union { __hip_bfloat16 h; unsigned short u; } c;
    c.h = __float2bfloat16(f);
    return c.u;
}

__device__ __forceinline__ s16x8 pack8(f32x4 lo, f32x4 hi) {
    s16x8 r;
    r[0] = (short)f2bf(lo[0]); r[1] = (short)f2bf(lo[1]);
    r[2] = (short)f2bf(lo[2]); r[3] = (short)f2bf(lo[3]);
    r[4] = (short)f2bf(hi[0]); r[5] = (short)f2bf(hi[1]);
    r[6] = (short)f2bf(hi[2]); r[7] = (short)f2bf(hi[3]);
    return r;
}

#define GLDS16(gp, lp)                                                         \
    __builtin_amdgcn_global_load_lds(                                          \
        (const __attribute__((address_space(1))) void*)(gp),                   \
        (__attribute__((address_space(3))) void*)(lp), 16, 0, 0)

// ---------------------------------------------------------------------------
// Kernel 0: pre-pack phi into per-(m,kk,lane) bf16 MFMA A-fragments so k1
// waves can load them with 16 fully-contiguous 1KB instructions.
// phiP[((m*4+kk)*64 + lane)*8] = 8 bf16 = phi[m*16+(lane&15)][kk*32+(lane>>4)*8 ..+8]
// ---------------------------------------------------------------------------
__global__ __launch_bounds__(256) void k0_prepack(
    const float* __restrict__ phi, unsigned short* __restrict__ phiP)
{
    const int t = threadIdx.x;
#pragma unroll
    for (int j = 0; j < 4; ++j) {
        int e = (j << 8) + t;               // 0..1023
        int lane = e & 63, mk = e >> 6;
        int m = mk >> 2, kk = mk & 3;
        int brow = lane & 15, quad = lane >> 4;
        const float* p = phi + ((m << 4) + brow) * C_ + kk * 32 + (quad << 3);
        s16x8 v = pack8(*(const f32x4*)p, *(const f32x4*)(p + 4));
        *(s16x8*)&phiP[e << 3] = v;
    }
}

// ---------------------------------------------------------------------------
// Kernel 1 v6: wave-private deep pipeline, ZERO barriers.
// 512 blocks (2/CU, fully resident) x 4 waves; wave owns 8i x 2k cells x
// all 64 b, loops 8 i-tiles. Per iter: 8 contiguous glds (dbuf, counted
// vmcnt(8)), swizzled ds_read -> pack -> 16 MFMA, trans bounce (48B
// stride), 2 coalesced 16B-chunk stores. Masked rows load a dup address
// (L1-hit) to keep vmcnt uniform. Blocks 512+: bias rows.
// ---------------------------------------------------------------------------
__global__ __launch_bounds__(256, 2) void k1_params(
    const unsigned short* __restrict__ phiP, const float* __restrict__ Wc,
    const float* __restrict__ bc, unsigned short* __restrict__ wT,
    float* __restrict__ biasWS, const float* __restrict__ phi)
{
    const int blk = blockIdx.x;
    const int tid = threadIdx.x;

    if (blk >= 512) {                       // ---- bias part ----
        int g = ((blk - 512) << 8) + tid;   // 0..32767
        int k = g >> 6, b = g & 63;
        const f32x4* w4 = (const f32x4*)(Wc + (size_t)(FF_ + k) * C_);
        const f32x4* p4 = (const f32x4*)(phi + b * C_);
        float acc = bc[FF_ + k];
#pragma unroll
        for (int c = 0; c < 32; ++c) {
            f32x4 a = w4[c], q = p4[c];
            acc += a[0]*q[0] + a[1]*q[1] + a[2]*q[2] + a[3]*q[3];
        }
        biasWS[(b << 9) + k] = acc;
        return;
    }

    __shared__ __align__(16) char stg[4][2][8192];            // 64 KB
    __shared__ __align__(16) unsigned short trans[4][64 * 24]; // 12 KB (48B b-stride)

    const int lane = tid & 63, wave = tid >> 6, quad = lane >> 4;
    const int kgrp = blk & 63, igrp = blk >> 6;   // 64 k-tiles x 8 i-groups
    const int k0 = kgrp << 3;
    const int kw = k0 + (wave << 1);              // this wave's 2 k's
    const int ibase = igrp << 6;                  // 64 i-rows per block

    // ---- A-fragments from phiP: 16 contiguous 1KB wave-loads
    s16x8 afr[4][4];
#pragma unroll
    for (int mk = 0; mk < 16; ++mk)
        afr[mk >> 2][mk & 3] = *(const s16x8*)&phiP[((mk << 6) + lane) << 3];

    // ---- per-lane cell coords
    const int c = lane & 15, il = c & 7, kl = c >> 3;
    const int kcell = kw + kl;
    const int dkc = kcell % 63;
    const int dk0 = kw % 63, dk1 = (kw + 1) % 63;
    const int dmin = dk0 < dk1 ? dk0 : dk1;

    // ---- prologue: bias values + keep bits for all 8 iters
    float bcv[8];
    unsigned keepm = 0;
#pragma unroll
    for (int t = 0; t < 8; ++t) {
        int icell = ibase + (t << 3) + il;
        bcv[t] = bc[icell * F_ + kcell];
        if ((icell % 63) >= dkc) keepm |= 1u << t;
    }

    const int rsel  = lane >> 5;
    const int sslot = (lane & 31) << 4;

    auto STAGE = [&](int t, int buf) {
        const int i0 = ibase + (t << 3);
#pragma unroll
        for (int g = 0; g < 8; ++g) {
            int r = i0 + g;
            int srow = ((r % 63) >= dmin) ? r : i0;   // dup masked rows (L1-hit)
            const char* src =
                (const char*)(Wc + ((size_t)srow * F_ + kw + rsel) * C_)
                + (sslot ^ (g << 4));
            GLDS16(src, &stg[wave][buf][g << 10]);
        }
    };

    STAGE(0, 0);

#pragma unroll
    for (int t = 0; t < 8; ++t) {
        if (t < 7) STAGE(t + 1, (t + 1) & 1);
        if (t < 7) asm volatile("s_waitcnt vmcnt(8)" ::: "memory");
        else       asm volatile("s_waitcnt vmcnt(0)" ::: "memory");

        f32x4 acc[4];
#pragma unroll
        for (int m = 0; m < 4; ++m) acc[m] = (f32x4){0.f, 0.f, 0.f, 0.f};

        const char* rowp = &stg[wave][t & 1][(il << 10) + (kl << 9)];
#pragma unroll
        for (int kk = 0; kk < 4; ++kk) {
            int y0 = (kk << 7) + (((quad << 5) | 0)  ^ (il << 4));
            int y1 = (kk << 7) + (((quad << 5) | 16) ^ (il << 4));
            s16x8 bfr = pack8(*(const f32x4*)(rowp + y0),
                              *(const f32x4*)(rowp + y1));
#pragma unroll
            for (int m = 0; m < 4; ++m)
                acc[m] = __builtin_amdgcn_mfma_f32_16x16x32_bf16(
                    afr[m][kk], bfr, acc[m], 0, 0, 0);
        }

        // ---- trans bounce (wave-private, no barrier)
        const bool keep = (keepm >> t) & 1;
        const float bv = bcv[t];
#pragma unroll
        for (int m = 0; m < 4; ++m)
#pragma unroll
            for (int r = 0; r < 4; ++r) {
                int b = (m << 4) + (quad << 2) + r;
                trans[wave][b * 24 + (kl << 3) + il] =
                    keep ? f2bf(acc[m][r] + bv) : (unsigned short)0;
            }

        // ---- readback + store: lane -> (b=lane); 2 x 16B chunks
        {
            const int i0 = ibase + (t << 3);
            s16x8 c0 = *(const s16x8*)&trans[wave][lane * 24];
            s16x8 c1 = *(const s16x8*)&trans[wave][lane * 24 + 8];
            *(s16x8*)&wT[(((size_t)((lane << 9) + kw))     << 9) + i0] = c0;
            *(s16x8*)&wT[(((size_t)((lane << 9) + kw + 1)) << 9) + i0] = c1;
        }
    }
}

// ---------------------------------------------------------------------------
// Kernel 2 (unchanged): two chained GEMMs vs wT + bias, residual epilogue.
// ---------------------------------------------------------------------------
#define SMEM_BOFF 66560           // 64*1040
#define CHUNK_B   32768
#define SMEM_TOT  (66560 + 2 * 32768)   // 132096

__global__ __launch_bounds__(512) void k2_apply(
    const float* __restrict__ X, const unsigned short* __restrict__ wT,
    const float* __restrict__ biasWS, float* __restrict__ out)
{
    extern __shared__ char smem[];
    unsigned short* A_lds = (unsigned short*)smem;

    const int blk = blockIdx.x;
    const int sw  = ((blk & 7) << 5) + (blk >> 3);   // XCD swizzle
    const int b   = sw >> 2;
    const int n0  = (sw & 3) << 6;

    const int tid = threadIdx.x, lane = tid & 63, wave = tid >> 6;
    const int wn = wave >> 2, wk = wave & 3;

    const float* Xb = X + (((size_t)(b * 256 + n0)) << 9);
    float*       Ob = out + (((size_t)(b * 256 + n0)) << 9);
    const unsigned short* wTb = wT + ((size_t)b << 18);

    float biasr[8];
#pragma unroll
    for (int nt = 0; nt < 8; ++nt)
        biasr[nt] = biasWS[(b << 9) + (wk << 7) + (nt << 4) + (lane & 15)];

    {
        const f32x4* X4 = (const f32x4*)Xb;
#pragma unroll
        for (int j = 0; j < 16; ++j) {
            int f = (j << 9) + tid;
            int row = f >> 7, c4 = f & 127;
            f32x4 v = X4[f];
            u16x4 h;
#pragma unroll
            for (int e = 0; e < 4; ++e) h[e] = f2bf(fmaxf(v[e], 0.f));
            *(u16x4*)&A_lds[row * 520 + (c4 << 2)] = h;
        }
    }

    const int srcslot = ((lane & 3) ^ ((lane >> 3) & 3)) << 3;

    f32x4 acc[2][8];

    for (int phase = 0; phase < 2; ++phase) {
#pragma unroll
        for (int mt = 0; mt < 2; ++mt)
#pragma unroll
            for (int nt = 0; nt < 8; ++nt) acc[mt][nt] = (f32x4){0.f, 0.f, 0.f, 0.f};

#pragma unroll
        for (int g = 0; g < 4; ++g) {
            int krow = (wave << 6) + (g << 4) + (lane >> 2);
            const unsigned short* src = wTb + ((size_t)krow << 9) + srcslot;
            char* lp = smem + SMEM_BOFF + (((wave << 6) + (g << 4)) << 6);
            GLDS16(src, lp);
        }
        asm volatile("s_waitcnt vmcnt(0)" ::: "memory");
        __syncthreads();

        for (int c = 0; c < 16; ++c) {
            const int cur = c & 1;
            if (c < 15) {
                const int i0n = (c + 1) << 5;
#pragma unroll
                for (int g = 0; g < 4; ++g) {
                    int krow = (wave << 6) + (g << 4) + (lane >> 2);
                    const unsigned short* src = wTb + ((size_t)krow << 9) + i0n + srcslot;
                    char* lp = smem + SMEM_BOFF + (cur ^ 1) * CHUNK_B
                             + (((wave << 6) + (g << 4)) << 6);
                    GLDS16(src, lp);
                }
            }
            const int i0c = c << 5;
            s16x8 afr[2];
#pragma unroll
            for (int mt = 0; mt < 2; ++mt) {
                int n = (wn << 5) + (mt << 4) + (lane & 15);
                afr[mt] = *(const s16x8*)&A_lds[n * 520 + i0c + ((lane >> 4) << 3)];
            }
            const unsigned short* Bb =
                (const unsigned short*)(smem + SMEM_BOFF + cur * CHUNK_B);
#pragma unroll
            for (int nt = 0; nt < 8; ++nt) {
                int k = (wk << 7) + (nt << 4) + (lane & 15);
                int slot = (((lane >> 4) ^ ((k >> 1) & 3)) << 3);
                s16x8 bfr = *(const s16x8*)&Bb[(k << 5) + slot];
#pragma unroll
                for (int mt = 0; mt < 2; ++mt)
                    acc[mt][nt] = __builtin_amdgcn_mfma_f32_16x16x32_bf16(
                        afr[mt], bfr, acc[mt][nt], 0, 0, 0);
            }
            asm volatile("s_waitcnt vmcnt(0)" ::: "memory");
            __syncthreads();
        }

        if (phase == 0) {
#pragma unroll
            for (int mt = 0; mt < 2; ++mt)
#pragma unroll
                for (int nt = 0; nt < 8; ++nt) {
                    int k = (wk << 7) + (nt << 4) + (lane & 15);
#pragma unroll
                    for (int r = 0; r < 4; ++r) {
                        int n = (wn << 5) + (mt << 4) + ((lane >> 4) << 2) + r;
                        A_lds[n * 520 + k] =
                            f2bf(fmaxf(acc[mt][nt][r] + biasr[nt], 0.f));
                    }
                }
            __syncthreads();
        }
    }

#pragma unroll
    for (int mt = 0; mt < 2; ++mt)
#pragma unroll
        for (int nt = 0; nt < 8; ++nt) {
            int k = (wk << 7) + (nt << 4) + (lane & 15);
#pragma unroll
            for (int r = 0; r < 4; ++r) {
                int n = (wn << 5) + (mt << 4) + ((lane >> 4) << 2) + r;
                size_t off = ((size_t)n << 9) + k;
                Ob[off] = Xb[off] + acc[mt][nt][r] + biasr[nt];
            }
        }
}

extern "C" void kernel_launch(void* const* d_in, const int* in_sizes, int n_in,
                              void* d_out, int out_size, void* d_ws, size_t ws_size,
                              hipStream_t stream) {
    const float* inputs = (const float*)d_in[0];
    const float* phi    = (const float*)d_in[1];
    const float* Wc     = (const float*)d_in[2];
    const float* bc     = (const float*)d_in[3];
    float* out = (float*)d_out;

    unsigned short* wT = (unsigned short*)d_ws;                          // 32 MiB
    float* biasWS = (float*)((char*)d_ws + (size_t)64 * 512 * 512 * 2);  // 128 KiB
    unsigned short* phiP =
        (unsigned short*)((char*)d_ws + (size_t)64 * 512 * 512 * 2 + 64 * 512 * 4);

    hipLaunchKernelGGL(k0_prepack, dim3(1), dim3(256), 0, stream, phi, phiP);

    hipLaunchKernelGGL(k1_params, dim3(640), dim3(256), 0, stream,
                       phiP, Wc, bc, wT, biasWS, phi);

    hipFuncSetAttribute((const void*)k2_apply,
                        hipFuncAttributeMaxDynamicSharedMemorySize, SMEM_TOT);
    hipLaunchKernelGGL(k2_apply, dim3(256), dim3(512), SMEM_TOT, stream,
                       inputs, wT, biasWS, out);
}

// Round 6
// 74.952 us; speedup vs baseline: 1.5152x; 1.1536x over previous
//
#include <hip/hip_runtime.h>
#include <hip/hip_bf16.h>

#define F_   512
#define FF_  (512 * 512)
#define C_   128

typedef __attribute__((ext_vector_type(4))) float f32x4;
typedef __attribute__((ext_vector_type(8))) short s16x8;
typedef __attribute__((ext_vector_type(4))) unsigned short u16x4;

__device__ __forceinline__ unsigned short f2bf(float f) {
    union { __hip_bfloat16 h; unsigned short u; } c;
    c.h = __float2bfloat16(f);
    return c.u;
}

__device__ __forceinline__ s16x8 pack8(f32x4 lo, f32x4 hi) {
    s16x8 r;
    r[0] = (short)f2bf(lo[0]); r[1] = (short)f2bf(lo[1]);
    r[2] = (short)f2bf(lo[2]); r[3] = (short)f2bf(lo[3]);
    r[4] = (short)f2bf(hi[0]); r[5] = (short)f2bf(hi[1]);
    r[6] = (short)f2bf(hi[2]); r[7] = (short)f2bf(hi[3]);
    return r;
}

#define GLDS16(gp, lp)                                                         \
    __builtin_amdgcn_global_load_lds(                                          \
        (const __attribute__((address_space(1))) void*)(gp),                   \
        (__attribute__((address_space(3))) void*)(lp), 16, 0, 0)

// ---------------------------------------------------------------------------
// Kernel 0: pre-pack phi -> per-(m,kk,lane) bf16 MFMA A-fragments.
// ---------------------------------------------------------------------------
__global__ __launch_bounds__(256) void k0_prepack(
    const float* __restrict__ phi, unsigned short* __restrict__ phiP)
{
    const int t = threadIdx.x;
#pragma unroll
    for (int j = 0; j < 4; ++j) {
        int e = (j << 8) + t;               // 0..1023
        int lane = e & 63, mk = e >> 6;
        int m = mk >> 2, kk = mk & 3;
        int brow = lane & 15, quad = lane >> 4;
        const float* p = phi + ((m << 4) + brow) * C_ + kk * 32 + (quad << 3);
        s16x8 v = pack8(*(const f32x4*)p, *(const f32x4*)(p + 4));
        *(s16x8*)&phiP[e << 3] = v;
    }
}

// ---------------------------------------------------------------------------
// Kernel 1 v7: v2 skeleton + counted vmcnt + slim afr + 16B-granule swizzle.
// Blocks 0..2047: tile 16i x 8k (i-major block order). 8 ct-iters; per ct:
// all 4 waves share one 8KB staged chunk (16 Wc rows, glds 1KB/inst,
// source-swizzled unit^row), each wave computes ONE m-tile (4 MFMA).
// NO VMEM stores in the loop; trans -> coalesced stores at block end.
// Blocks 2048+: bias rows.
// ---------------------------------------------------------------------------
__global__ __launch_bounds__(256, 4) void k1_params(
    const unsigned short* __restrict__ phiP, const float* __restrict__ Wc,
    const float* __restrict__ bc, unsigned short* __restrict__ wT,
    float* __restrict__ biasWS, const float* __restrict__ phi)
{
    const int blk = blockIdx.x;
    const int tid = threadIdx.x;

    if (blk >= 2048) {                      // ---- bias part ----
        int g = ((blk - 2048) << 8) + tid;  // 0..32767
        int k = g >> 6, b = g & 63;
        const f32x4* w4 = (const f32x4*)(Wc + (size_t)(FF_ + k) * C_);
        const f32x4* p4 = (const f32x4*)(phi + b * C_);
        float acc = bc[FF_ + k];
#pragma unroll
        for (int c = 0; c < 32; ++c) {
            f32x4 a = w4[c], q = p4[c];
            acc += a[0]*q[0] + a[1]*q[1] + a[2]*q[2] + a[3]*q[3];
        }
        biasWS[(b << 9) + k] = acc;
        return;
    }

    __shared__ __align__(16) float stg[2][2048];             // 2 x 8 KB
    __shared__ __align__(16) unsigned short trans[64 * 136]; // 17.4 KB

    const int lane = tid & 63, wave = tid >> 6, quad = lane >> 4;
    const int i0 = (blk & 31) << 4;     // i-major: co-dispatched blocks share k
    const int k0 = (blk >> 5) << 3;

    // ---- afr: this wave's m-tile, 4 x 1KB contiguous loads from phiP
    s16x8 afr[4];
#pragma unroll
    for (int kk = 0; kk < 4; ++kk)
        afr[kk] = *(const s16x8*)&phiP[(((wave << 2) + kk) << 6 | lane) << 3];

    // ---- per-lane cell coords (D col c16 -> (di, kq))
    const int c16 = lane & 15;
    const int di = c16 >> 3, kq = c16 & 7;
    const int kcur = k0 + kq;
    const int dk = kcur % 63;

    // ---- skip mask + keep bits + bias values
    int kmin = 63;
#pragma unroll
    for (int kk = 0; kk < 8; ++kk) { int d = (k0 + kk) % 63; kmin = d < kmin ? d : kmin; }
    unsigned skipm = 0, keepm = 0;
    float bcv[8];
#pragma unroll
    for (int ct = 0; ct < 8; ++ct) {
        int a = (i0 + 2 * ct) % 63, b2 = (i0 + 2 * ct + 1) % 63;
        if ((a > b2 ? a : b2) < kmin) skipm |= 1u << ct;
        int icur = i0 + 2 * ct + di;
        if ((icur % 63) >= dk) keepm |= 1u << ct;
        bcv[ct] = bc[icur * F_ + kcur];
    }

    // ---- staging geometry: wave stages rows rr = wave*4 + e*2 + (lane>>5)
    const int u = lane & 31;            // 16B unit within 512B row

    auto STAGE = [&](int ct, int buf) {
#pragma unroll
        for (int e = 0; e < 2; ++e) {
            int rr = (wave << 2) + (e << 1) + (lane >> 5);
            int p  = (i0 + 2 * ct + (rr >> 3)) * F_ + k0 + (rr & 7);
            const char* src = (const char*)(Wc + (size_t)p * C_)
                            + ((u ^ rr) << 4);          // pre-swizzled source
            GLDS16(src, (char*)stg[buf] + (((wave << 2) + (e << 1)) << 9));
        }
    };

    bool cur = !(skipm & 1u);
    if (cur) STAGE(0, 0);

    for (int ct = 0; ct < 8; ++ct) {
        const bool nxt = (ct < 7) && !((skipm >> (ct + 1)) & 1u);
        if (nxt) STAGE(ct + 1, (ct + 1) & 1);
        if (cur) {
            if (nxt) asm volatile("s_waitcnt vmcnt(2)" ::: "memory");
            else     asm volatile("s_waitcnt vmcnt(0)" ::: "memory");
        }
        __builtin_amdgcn_s_barrier();

        f32x4 acc = (f32x4){0.f, 0.f, 0.f, 0.f};
        if (cur) {
            const char* base = (const char*)stg[ct & 1] + (c16 << 9);
#pragma unroll
            for (int kk = 0; kk < 4; ++kk) {
                int ul = (kk << 3) + (quad << 1);
                f32x4 lo = *(const f32x4*)(base + (( ul      ^ c16) << 4));
                f32x4 hi = *(const f32x4*)(base + (((ul + 1) ^ c16) << 4));
                acc = __builtin_amdgcn_mfma_f32_16x16x32_bf16(
                    afr[kk], pack8(lo, hi), acc, 0, 0, 0);
            }
        }

        // trans write (always; zeros for skipped/masked cells)
        const bool kp = cur && ((keepm >> ct) & 1);
        const float bv = bcv[ct];
        const int ii = 2 * ct + di;
#pragma unroll
        for (int r = 0; r < 4; ++r) {
            int b = (wave << 4) + (quad << 2) + r;
            trans[b * 136 + (kq << 4) + ii] =
                kp ? f2bf(acc[r] + bv) : (unsigned short)0;
        }
        __builtin_amdgcn_s_barrier();
        cur = nxt;
    }
    __syncthreads();

    // ---- store: 64b x 8k x 16i -> wT, 32B per (b,k) row, 2-lane runs
#pragma unroll
    for (int j = 0; j < 4; ++j) {
        int q = (j << 8) + tid;             // 0..1023
        int b = q >> 4, k = (q >> 1) & 7, h = q & 1;
        s16x8 v = *(const s16x8*)&trans[b * 136 + (k << 4) + (h << 3)];
        *(s16x8*)&wT[(((size_t)((b << 9) + k0 + k)) << 9) + i0 + (h << 3)] = v;
    }
}

// ---------------------------------------------------------------------------
// Kernel 2 (unchanged): two chained GEMMs vs wT + bias, residual epilogue.
// ---------------------------------------------------------------------------
#define SMEM_BOFF 66560           // 64*1040
#define CHUNK_B   32768
#define SMEM_TOT  (66560 + 2 * 32768)   // 132096

__global__ __launch_bounds__(512) void k2_apply(
    const float* __restrict__ X, const unsigned short* __restrict__ wT,
    const float* __restrict__ biasWS, float* __restrict__ out)
{
    extern __shared__ char smem[];
    unsigned short* A_lds = (unsigned short*)smem;

    const int blk = blockIdx.x;
    const int sw  = ((blk & 7) << 5) + (blk >> 3);   // XCD swizzle
    const int b   = sw >> 2;
    const int n0  = (sw & 3) << 6;

    const int tid = threadIdx.x, lane = tid & 63, wave = tid >> 6;
    const int wn = wave >> 2, wk = wave & 3;

    const float* Xb = X + (((size_t)(b * 256 + n0)) << 9);
    float*       Ob = out + (((size_t)(b * 256 + n0)) << 9);
    const unsigned short* wTb = wT + ((size_t)b << 18);

    float biasr[8];
#pragma unroll
    for (int nt = 0; nt < 8; ++nt)
        biasr[nt] = biasWS[(b << 9) + (wk << 7) + (nt << 4) + (lane & 15)];

    {
        const f32x4* X4 = (const f32x4*)Xb;
#pragma unroll
        for (int j = 0; j < 16; ++j) {
            int f = (j << 9) + tid;
            int row = f >> 7, c4 = f & 127;
            f32x4 v = X4[f];
            u16x4 h;
#pragma unroll
            for (int e = 0; e < 4; ++e) h[e] = f2bf(fmaxf(v[e], 0.f));
            *(u16x4*)&A_lds[row * 520 + (c4 << 2)] = h;
        }
    }

    const int srcslot = ((lane & 3) ^ ((lane >> 3) & 3)) << 3;

    f32x4 acc[2][8];

    for (int phase = 0; phase < 2; ++phase) {
#pragma unroll
        for (int mt = 0; mt < 2; ++mt)
#pragma unroll
            for (int nt = 0; nt < 8; ++nt) acc[mt][nt] = (f32x4){0.f, 0.f, 0.f, 0.f};

#pragma unroll
        for (int g = 0; g < 4; ++g) {
            int krow = (wave << 6) + (g << 4) + (lane >> 2);
            const unsigned short* src = wTb + ((size_t)krow << 9) + srcslot;
            char* lp = smem + SMEM_BOFF + (((wave << 6) + (g << 4)) << 6);
            GLDS16(src, lp);
        }
        asm volatile("s_waitcnt vmcnt(0)" ::: "memory");
        __syncthreads();

        for (int c = 0; c < 16; ++c) {
            const int cur = c & 1;
            if (c < 15) {
                const int i0n = (c + 1) << 5;
#pragma unroll
                for (int g = 0; g < 4; ++g) {
                    int krow = (wave << 6) + (g << 4) + (lane >> 2);
                    const unsigned short* src = wTb + ((size_t)krow << 9) + i0n + srcslot;
                    char* lp = smem + SMEM_BOFF + (cur ^ 1) * CHUNK_B
                             + (((wave << 6) + (g << 4)) << 6);
                    GLDS16(src, lp);
                }
            }
            const int i0c = c << 5;
            s16x8 afr[2];
#pragma unroll
            for (int mt = 0; mt < 2; ++mt) {
                int n = (wn << 5) + (mt << 4) + (lane & 15);
                afr[mt] = *(const s16x8*)&A_lds[n * 520 + i0c + ((lane >> 4) << 3)];
            }
            const unsigned short* Bb =
                (const unsigned short*)(smem + SMEM_BOFF + cur * CHUNK_B);
#pragma unroll
            for (int nt = 0; nt < 8; ++nt) {
                int k = (wk << 7) + (nt << 4) + (lane & 15);
                int slot = (((lane >> 4) ^ ((k >> 1) & 3)) << 3);
                s16x8 bfr = *(const s16x8*)&Bb[(k << 5) + slot];
#pragma unroll
                for (int mt = 0; mt < 2; ++mt)
                    acc[mt][nt] = __builtin_amdgcn_mfma_f32_16x16x32_bf16(
                        afr[mt], bfr, acc[mt][nt], 0, 0, 0);
            }
            asm volatile("s_waitcnt vmcnt(0)" ::: "memory");
            __syncthreads();
        }

        if (phase == 0) {
#pragma unroll
            for (int mt = 0; mt < 2; ++mt)
#pragma unroll
                for (int nt = 0; nt < 8; ++nt) {
                    int k = (wk << 7) + (nt << 4) + (lane & 15);
#pragma unroll
                    for (int r = 0; r < 4; ++r) {
                        int n = (wn << 5) + (mt << 4) + ((lane >> 4) << 2) + r;
                        A_lds[n * 520 + k] =
                            f2bf(fmaxf(acc[mt][nt][r] + biasr[nt], 0.f));
                    }
                }
            __syncthreads();
        }
    }

#pragma unroll
    for (int mt = 0; mt < 2; ++mt)
#pragma unroll
        for (int nt = 0; nt < 8; ++nt) {
            int k = (wk << 7) + (nt << 4) + (lane & 15);
#pragma unroll
            for (int r = 0; r < 4; ++r) {
                int n = (wn << 5) + (mt << 4) + ((lane >> 4) << 2) + r;
                size_t off = ((size_t)n << 9) + k;
                Ob[off] = Xb[off] + acc[mt][nt][r] + biasr[nt];
            }
        }
}

extern "C" void kernel_launch(void* const* d_in, const int* in_sizes, int n_in,
                              void* d_out, int out_size, void* d_ws, size_t ws_size,
                              hipStream_t stream) {
    const float* inputs = (const float*)d_in[0];
    const float* phi    = (const float*)d_in[1];
    const float* Wc     = (const float*)d_in[2];
    const float* bc     = (const float*)d_in[3];
    float* out = (float*)d_out;

    unsigned short* wT = (unsigned short*)d_ws;                          // 32 MiB
    float* biasWS = (float*)((char*)d_ws + (size_t)64 * 512 * 512 * 2);  // 128 KiB
    unsigned short* phiP =
        (unsigned short*)((char*)d_ws + (size_t)64 * 512 * 512 * 2 + 64 * 512 * 4);

    hipLaunchKernelGGL(k0_prepack, dim3(1), dim3(256), 0, stream, phi, phiP);

    hipLaunchKernelGGL(k1_params, dim3(2176), dim3(256), 0, stream,
                       phiP, Wc, bc, wT, biasWS, phi);

    hipFuncSetAttribute((const void*)k2_apply,
                        hipFuncAttributeMaxDynamicSharedMemorySize, SMEM_TOT);
    hipLaunchKernelGGL(k2_apply, dim3(256), dim3(512), SMEM_TOT, stream,
                       inputs, wT, biasWS, out);
}

// Round 7
// 71.793 us; speedup vs baseline: 1.5819x; 1.0440x over previous
//
#include <hip/hip_runtime.h>
#include <hip/hip_bf16.h>

#define F_   512
#define FF_  (512 * 512)
#define C_   128

typedef __attribute__((ext_vector_type(4))) float f32x4;
typedef __attribute__((ext_vector_type(8))) short s16x8;
typedef __attribute__((ext_vector_type(4))) unsigned short u16x4;

__device__ __forceinline__ unsigned short f2bf(float f) {
    union { __hip_bfloat16 h; unsigned short u; } c;
    c.h = __float2bfloat16(f);
    return c.u;
}

__device__ __forceinline__ s16x8 pack8(f32x4 lo, f32x4 hi) {
    s16x8 r;
    r[0] = (short)f2bf(lo[0]); r[1] = (short)f2bf(lo[1]);
    r[2] = (short)f2bf(lo[2]); r[3] = (short)f2bf(lo[3]);
    r[4] = (short)f2bf(hi[0]); r[5] = (short)f2bf(hi[1]);
    r[6] = (short)f2bf(hi[2]); r[7] = (short)f2bf(hi[3]);
    return r;
}

#define GLDS16(gp, lp)                                                         \
    __builtin_amdgcn_global_load_lds(                                          \
        (const __attribute__((address_space(1))) void*)(gp),                   \
        (__attribute__((address_space(3))) void*)(lp), 16, 0, 0)

// ---------------------------------------------------------------------------
// Kernel 0: pre-pack phi -> per-(bt,kk,lane) bf16 MFMA B-fragments.
// frag elem: lane l holds phi[bt*16 + (l&15)][kk*32 + (l>>4)*8 .. +8].
// ---------------------------------------------------------------------------
__global__ __launch_bounds__(256) void k0_prepack(
    const float* __restrict__ phi, unsigned short* __restrict__ phiP)
{
    const int t = threadIdx.x;
#pragma unroll
    for (int j = 0; j < 4; ++j) {
        int e = (j << 8) + t;               // 0..1023
        int lane = e & 63, mk = e >> 6;
        int m = mk >> 2, kk = mk & 3;
        int brow = lane & 15, quad = lane >> 4;
        const float* p = phi + ((m << 4) + brow) * C_ + kk * 32 + (quad << 3);
        s16x8 v = pack8(*(const f32x4*)p, *(const f32x4*)(p + 4));
        *(s16x8*)&phiP[e << 3] = v;
    }
}

// ---------------------------------------------------------------------------
// Kernel 1 v9: operand-swapped, wave-private, BARRIER-FREE.
// D = A(Wc rows: M=16 i-cells, one k) x B(phi: N=16 b) -> lane's 4 regs are
// 4 CONSECUTIVE i for fixed (b,k): pack ushort4, store straight to
// wT[b][k][i]. No LDS transpose, no barriers. Per wave: own (16i x 8k)
// region, 8 iters; per iter: 8 contiguous glds (dbuf, uniform counted
// vmcnt), 8 swizzled ds_read_b128, 16 MFMA, 4 x 8B-per-lane stores.
// Fully-masked k: skip compute, stage dup rows (L1 hit, vmcnt uniform).
// Blocks 0..511 compute (2/CU); 512..639 bias rows.
// ---------------------------------------------------------------------------
__global__ __launch_bounds__(256, 2) void k1_params(
    const unsigned short* __restrict__ phiP, const float* __restrict__ Wc,
    const float* __restrict__ bc, unsigned short* __restrict__ wT,
    float* __restrict__ biasWS, const float* __restrict__ phi)
{
    const int blk = blockIdx.x;
    const int tid = threadIdx.x;

    if (blk >= 512) {                       // ---- bias part ----
        int g = ((blk - 512) << 8) + tid;   // 0..32767
        int k = g >> 6, b = g & 63;
        const f32x4* w4 = (const f32x4*)(Wc + (size_t)(FF_ + k) * C_);
        const f32x4* p4 = (const f32x4*)(phi + b * C_);
        float acc = bc[FF_ + k];
#pragma unroll
        for (int c = 0; c < 32; ++c) {
            f32x4 a = w4[c], q = p4[c];
            acc += a[0]*q[0] + a[1]*q[1] + a[2]*q[2] + a[3]*q[3];
        }
        biasWS[(b << 9) + k] = acc;
        return;
    }

    __shared__ __align__(16) char stg[4][2][8192];   // wave-private dbuf, 64 KB

    const int lane = tid & 63, wave = tid >> 6, quad = lane >> 4;
    const int w  = (blk << 2) + wave;       // global wave id 0..2047
    const int i0 = (w & 31) << 4;           // 32 i-tiles of 16
    const int k0 = (w >> 5) << 3;           // 64 k-octets

    // ---- B-fragments (phi) from phiP: 16 contiguous 1KB loads (64 VGPR)
    s16x8 bfrP[4][4];
#pragma unroll
    for (int mk = 0; mk < 16; ++mk)
        bfrP[mk >> 2][mk & 3] = *(const s16x8*)&phiP[((mk << 6) + lane) << 3];

    // ---- bias regs: bias[rr][ct] = bc[(i0+quad*4+rr)*512 + k0+ct]
    f32x4 biasv[4][2];
#pragma unroll
    for (int rr = 0; rr < 4; ++rr) {
        const float* p = bc + (i0 + (quad << 2) + rr) * F_ + k0;
        biasv[rr][0] = *(const f32x4*)p;
        biasv[rr][1] = *(const f32x4*)(p + 4);
    }

    // ---- keep bits: bit(ct*4+rr) = d_i >= d_k ; per-ct wave-uniform skip
    unsigned keepm = 0;
    {
#pragma unroll
        for (int ct = 0; ct < 8; ++ct) {
            int dk = (k0 + ct) % 63;
#pragma unroll
            for (int rr = 0; rr < 4; ++rr) {
                int di = (i0 + (quad << 2) + rr) % 63;
                if (di >= dk) keepm |= 1u << ((ct << 2) + rr);
            }
        }
    }
    int maxd = i0 % 63 + 15; maxd = maxd > 62 ? 62 : maxd;
    unsigned skipm = 0;
#pragma unroll
    for (int ct = 0; ct < 8; ++ct)
        if (((k0 + ct) % 63) > maxd) skipm |= 1u << ct;

    // ---- staging: 8 glds/tile; glds j covers rows 2j,2j+1 (row = i-local)
    const int r2 = lane >> 5, s = lane & 31;
    char* const stw0 = stg[wave][0];
    char* const stw1 = stg[wave][1];

    auto STAGE = [&](int ct, char* dst) {
        const bool sk = (skipm >> ct) & 1;
        const int  k  = k0 + ct;
#pragma unroll
        for (int j = 0; j < 8; ++j) {
            int row = (j << 1) + r2;
            int isrc = sk ? i0 : (i0 + row);          // dup row when skipped
            const char* src = (const char*)(Wc + ((size_t)(isrc * F_ + k)) * C_)
                            + ((s << 4) ^ ((row & 7) << 6));
            GLDS16(src, dst + (row << 9) + ((s << 4) ^ ((row & 7) << 6)));
        }
    };
    // NOTE dest above: linear per lane = j*1024 + r2*512 + s*16 == row*512+s*16
    // but we wrote swizzled form; glds dest MUST be base+lane*16. Fix: dest
    // linear, source carries the swizzle (rule 21). See corrected call below.

    // drain prologue loads so counted vmcnt is exact
    asm volatile("s_waitcnt vmcnt(0)" ::: "memory");

    // corrected STAGE (linear dest):
    auto STAGE2 = [&](int ct, char* dst) {
        const bool sk = (skipm >> ct) & 1;
        const int  k  = k0 + ct;
#pragma unroll
        for (int j = 0; j < 8; ++j) {
            int row = (j << 1) + r2;
            int isrc = sk ? i0 : (i0 + row);
            const char* src = (const char*)(Wc + ((size_t)(isrc * F_ + k)) * C_)
                            + ((s << 4) ^ ((row & 7) << 6));
            GLDS16(src, dst + (j << 10));   // + lane*16 implicit -> row*512+s*16
        }
    };
    (void)STAGE;

    STAGE2(0, stw0);

#pragma unroll
    for (int ct = 0; ct < 8; ++ct) {
        char* bufc = (ct & 1) ? stw1 : stw0;
        if (ct < 7) STAGE2(ct + 1, (ct & 1) ? stw0 : stw1);

        if (ct == 0)      asm volatile("s_waitcnt vmcnt(8)"  ::: "memory");
        else if (ct < 7)  asm volatile("s_waitcnt vmcnt(12)" ::: "memory");
        else              asm volatile("s_waitcnt vmcnt(4)"  ::: "memory");
        __builtin_amdgcn_sched_barrier(0);

        f32x4 acc[4];
#pragma unroll
        for (int bt = 0; bt < 4; ++bt) acc[bt] = (f32x4){0.f, 0.f, 0.f, 0.f};

        const bool sk = (skipm >> ct) & 1;
        if (!sk) {
            const int rowB = (lane & 15) << 9;      // row*512
            const int swz  = (lane & 7) << 6;
#pragma unroll
            for (int kk = 0; kk < 4; ++kk) {
                int x0 = ((kk << 7) + (quad << 5)) ^ swz;
                int x1 = ((kk << 7) + (quad << 5) + 16) ^ swz;
                f32x4 lo = *(const f32x4*)(bufc + rowB + x0);
                f32x4 hi = *(const f32x4*)(bufc + rowB + x1);
                s16x8 aW = pack8(lo, hi);
#pragma unroll
                for (int bt = 0; bt < 4; ++bt)
                    acc[bt] = __builtin_amdgcn_mfma_f32_16x16x32_bf16(
                        aW, bfrP[bt][kk], acc[bt], 0, 0, 0);
            }
        }

        // ---- direct store: lane's 4 regs = i0+quad*4+rr for (b, k0+ct)
        const int k = k0 + ct;
#pragma unroll
        for (int bt = 0; bt < 4; ++bt) {
            u16x4 v;
#pragma unroll
            for (int rr = 0; rr < 4; ++rr) {
                bool kp = (!sk) && ((keepm >> ((ct << 2) + rr)) & 1);
                float bv = (ct < 4) ? biasv[rr][0][ct] : biasv[rr][1][ct - 4];
                v[rr] = kp ? f2bf(acc[bt][rr] + bv) : (unsigned short)0;
            }
            int b = (bt << 4) + (lane & 15);
            *(u16x4*)&wT[(((size_t)((b << 9) + k)) << 9) + i0 + (quad << 2)] = v;
        }
    }
}

// ---------------------------------------------------------------------------
// Kernel 2 (unchanged): two chained GEMMs vs wT + bias, residual epilogue.
// ---------------------------------------------------------------------------
#define SMEM_BOFF 66560           // 64*1040
#define CHUNK_B   32768
#define SMEM_TOT  (66560 + 2 * 32768)   // 132096

__global__ __launch_bounds__(512) void k2_apply(
    const float* __restrict__ X, const unsigned short* __restrict__ wT,
    const float* __restrict__ biasWS, float* __restrict__ out)
{
    extern __shared__ char smem[];
    unsigned short* A_lds = (unsigned short*)smem;

    const int blk = blockIdx.x;
    const int sw  = ((blk & 7) << 5) + (blk >> 3);   // XCD swizzle
    const int b   = sw >> 2;
    const int n0  = (sw & 3) << 6;

    const int tid = threadIdx.x, lane = tid & 63, wave = tid >> 6;
    const int wn = wave >> 2, wk = wave & 3;

    const float* Xb = X + (((size_t)(b * 256 + n0)) << 9);
    float*       Ob = out + (((size_t)(b * 256 + n0)) << 9);
    const unsigned short* wTb = wT + ((size_t)b << 18);

    float biasr[8];
#pragma unroll
    for (int nt = 0; nt < 8; ++nt)
        biasr[nt] = biasWS[(b << 9) + (wk << 7) + (nt << 4) + (lane & 15)];

    {
        const f32x4* X4 = (const f32x4*)Xb;
#pragma unroll
        for (int j = 0; j < 16; ++j) {
            int f = (j << 9) + tid;
            int row = f >> 7, c4 = f & 127;
            f32x4 v = X4[f];
            u16x4 h;
#pragma unroll
            for (int e = 0; e < 4; ++e) h[e] = f2bf(fmaxf(v[e], 0.f));
            *(u16x4*)&A_lds[row * 520 + (c4 << 2)] = h;
        }
    }

    const int srcslot = ((lane & 3) ^ ((lane >> 3) & 3)) << 3;

    f32x4 acc[2][8];

    for (int phase = 0; phase < 2; ++phase) {
#pragma unroll
        for (int mt = 0; mt < 2; ++mt)
#pragma unroll
            for (int nt = 0; nt < 8; ++nt) acc[mt][nt] = (f32x4){0.f, 0.f, 0.f, 0.f};

#pragma unroll
        for (int g = 0; g < 4; ++g) {
            int krow = (wave << 6) + (g << 4) + (lane >> 2);
            const unsigned short* src = wTb + ((size_t)krow << 9) + srcslot;
            char* lp = smem + SMEM_BOFF + (((wave << 6) + (g << 4)) << 6);
            GLDS16(src, lp);
        }
        asm volatile("s_waitcnt vmcnt(0)" ::: "memory");
        __syncthreads();

        for (int c = 0; c < 16; ++c) {
            const int cur = c & 1;
            if (c < 15) {
                const int i0n = (c + 1) << 5;
#pragma unroll
                for (int g = 0; g < 4; ++g) {
                    int krow = (wave << 6) + (g << 4) + (lane >> 2);
                    const unsigned short* src = wTb + ((size_t)krow << 9) + i0n + srcslot;
                    char* lp = smem + SMEM_BOFF + (cur ^ 1) * CHUNK_B
                             + (((wave << 6) + (g << 4)) << 6);
                    GLDS16(src, lp);
                }
            }
            const int i0c = c << 5;
            s16x8 afr[2];
#pragma unroll
            for (int mt = 0; mt < 2; ++mt) {
                int n = (wn << 5) + (mt << 4) + (lane & 15);
                afr[mt] = *(const s16x8*)&A_lds[n * 520 + i0c + ((lane >> 4) << 3)];
            }
            const unsigned short* Bb =
                (const unsigned short*)(smem + SMEM_BOFF + cur * CHUNK_B);
#pragma unroll
            for (int nt = 0; nt < 8; ++nt) {
                int k = (wk << 7) + (nt << 4) + (lane & 15);
                int slot = (((lane >> 4) ^ ((k >> 1) & 3)) << 3);
                s16x8 bfr = *(const s16x8*)&Bb[(k << 5) + slot];
#pragma unroll
                for (int mt = 0; mt < 2; ++mt)
                    acc[mt][nt] = __builtin_amdgcn_mfma_f32_16x16x32_bf16(
                        afr[mt], bfr, acc[mt][nt], 0, 0, 0);
            }
            asm volatile("s_waitcnt vmcnt(0)" ::: "memory");
            __syncthreads();
        }

        if (phase == 0) {
#pragma unroll
            for (int mt = 0; mt < 2; ++mt)
#pragma unroll
                for (int nt = 0; nt < 8; ++nt) {
                    int k = (wk << 7) + (nt << 4) + (lane & 15);
#pragma unroll
                    for (int r = 0; r < 4; ++r) {
                        int n = (wn << 5) + (mt << 4) + ((lane >> 4) << 2) + r;
                        A_lds[n * 520 + k] =
                            f2bf(fmaxf(acc[mt][nt][r] + biasr[nt], 0.f));
                    }
                }
            __syncthreads();
        }
    }

#pragma unroll
    for (int mt = 0; mt < 2; ++mt)
#pragma unroll
        for (int nt = 0; nt < 8; ++nt) {
            int k = (wk << 7) + (nt << 4) + (lane & 15);
#pragma unroll
            for (int r = 0; r < 4; ++r) {
                int n = (wn << 5) + (mt << 4) + ((lane >> 4) << 2) + r;
                size_t off = ((size_t)n << 9) + k;
                Ob[off] = Xb[off] + acc[mt][nt][r] + biasr[nt];
            }
        }
}

extern "C" void kernel_launch(void* const* d_in, const int* in_sizes, int n_in,
                              void* d_out, int out_size, void* d_ws, size_t ws_size,
                              hipStream_t stream) {
    const float* inputs = (const float*)d_in[0];
    const float* phi    = (const float*)d_in[1];
    const float* Wc     = (const float*)d_in[2];
    const float* bc     = (const float*)d_in[3];
    float* out = (float*)d_out;

    unsigned short* wT = (unsigned short*)d_ws;                          // 32 MiB
    float* biasWS = (float*)((char*)d_ws + (size_t)64 * 512 * 512 * 2);  // 128 KiB
    unsigned short* phiP =
        (unsigned short*)((char*)d_ws + (size_t)64 * 512 * 512 * 2 + 64 * 512 * 4);

    hipLaunchKernelGGL(k0_prepack, dim3(1), dim3(256), 0, stream, phi, phiP);

    hipLaunchKernelGGL(k1_params, dim3(640), dim3(256), 0, stream,
                       phiP, Wc, bc, wT, biasWS, phi);

    hipFuncSetAttribute((const void*)k2_apply,
                        hipFuncAttributeMaxDynamicSharedMemorySize, SMEM_TOT);
    hipLaunchKernelGGL(k2_apply, dim3(256), dim3(512), SMEM_TOT, stream,
                       inputs, wT, biasWS, out);
}